// Round 1
// baseline (537.602 us; speedup 1.0000x reference)
//
#include <hip/hip_runtime.h>
#include <hip/hip_bf16.h>

// GAT-style fused masked attention, B=4 N=4096 D=128, fp32 in/out.
// out = softmax(mask(X X^T / sqrt(D), adj)) @ X
// Strategy: bf16 MFMA (16x16x32) for both GEMMs, fp32 softmax without
// max-subtraction (scores ~N(0,1), exp never overflows fp32).
// Per block: 4 waves x 16 q-rows = 64 rows; key tiles of 128 staged in LDS
// twice ([key][d] for QK^T B-frags, [d][key] for PV B-frags).

#define NN 4096
#define DD 128
#define BK 128
#define BM 64

#define XB_STRIDE 272                      // [128 keys][136 bf16] padded
#define XBT_STRIDE 264                     // [128 d][132 bf16] padded (b64 ops)
#define P_STRIDE 272                       // per wave [16 q][136 bf16]
#define XB_OFF 0
#define XBT_OFF (128 * XB_STRIDE)          // 34816
#define P_OFF (XBT_OFF + 128 * XBT_STRIDE) // 68608
#define P_WAVE (16 * P_STRIDE)             // 4352
#define LDS_BYTES (P_OFF + 4 * P_WAVE)     // 86016 (<160K, 1 block/CU)

typedef __attribute__((ext_vector_type(8))) short bf16x8;
typedef __attribute__((ext_vector_type(4))) float f32x4;

static __device__ __forceinline__ unsigned f2bf(float f) {
    union { float f; unsigned u; } v; v.f = f;
    unsigned r = v.u + 0x7fffu + ((v.u >> 16) & 1u);  // RNE
    return r >> 16;
}

__global__ __launch_bounds__(256, 1)
void gat_fused(const float* __restrict__ X, const int* __restrict__ adj,
               float* __restrict__ out) {
    extern __shared__ char lds[];
    const int t   = threadIdx.x;
    const int w   = t >> 6;    // wave 0..3
    const int l   = t & 63;
    const int h   = l >> 4;    // 16-lane group 0..3
    const int l16 = l & 15;

    const int bid   = blockIdx.x;
    const int b     = bid >> 6;           // batch
    const int row0  = (bid & 63) * BM;    // 64 row-blocks per batch
    const int qbase = row0 + w * 16;      // wave's 16 q rows

    const float* Xg = X   + (size_t)b * NN * DD;
    const int*   Ag = adj + (size_t)b * NN * NN;
    float*       Og = out + (size_t)b * NN * DD;

    // ---- hoist Q A-frags (A[row=l16][k=8h+i+32*ds]) into registers ----
    bf16x8 qfrag[4];
    {
        const float* qrow = Xg + (size_t)(qbase + l16) * DD + h * 8;
        #pragma unroll
        for (int ds = 0; ds < 4; ++ds) {
            float4 a = *(const float4*)(qrow + ds * 32);
            float4 c = *(const float4*)(qrow + ds * 32 + 4);
            union { bf16x8 v; unsigned u[4]; } q;
            q.u[0] = f2bf(a.x) | (f2bf(a.y) << 16);
            q.u[1] = f2bf(a.z) | (f2bf(a.w) << 16);
            q.u[2] = f2bf(c.x) | (f2bf(c.y) << 16);
            q.u[3] = f2bf(c.z) | (f2bf(c.w) << 16);
            qfrag[ds] = q.v;
        }
    }

    f32x4 oacc[8];
    #pragma unroll
    for (int cf = 0; cf < 8; ++cf) oacc[cf] = (f32x4){0.f, 0.f, 0.f, 0.f};
    float psum[4] = {0.f, 0.f, 0.f, 0.f};

    for (int kt = 0; kt < NN / BK; ++kt) {
        const int key0 = kt * BK;

        // ---- prefetch adj for this tile (no LDS dependency; hides HBM) ----
        int av[8][4];
        #pragma unroll
        for (int kf = 0; kf < 8; ++kf)
            #pragma unroll
            for (int r = 0; r < 4; ++r)
                av[kf][r] = Ag[(size_t)(qbase + h * 4 + r) * NN + key0 + kf * 16 + l16];

        __syncthreads();  // prior-tile readers done before restaging

        // ---- stage Xb [key][d] bf16 (coalesced float4 loads) ----
        {
            const float* src = Xg + (size_t)key0 * DD;
            #pragma unroll
            for (int it = 0; it < 16; ++it) {
                int k  = it * 8 + (t >> 5);
                int d4 = (t & 31) * 4;
                float4 v = *(const float4*)(src + (size_t)k * DD + d4);
                uint2 pk;
                pk.x = f2bf(v.x) | (f2bf(v.y) << 16);
                pk.y = f2bf(v.z) | (f2bf(v.w) << 16);
                *(uint2*)(lds + XB_OFF + k * XB_STRIDE + d4 * 2) = pk;
            }
        }
        __syncthreads();

        // ---- in-LDS transpose: XbT[d][key]  (known ~8-way on writes) ----
        {
            #pragma unroll
            for (int it = 0; it < 8; ++it) {
                int f  = it * 256 + t;   // 0..2047 = 64 d-pairs x 32 key-groups
                int dp = f & 63;
                int g  = f >> 6;
                int d0 = dp * 2;
                const char* base = lds + XB_OFF + (4 * g) * XB_STRIDE + d0 * 2;
                unsigned r0 = *(const unsigned*)(base);
                unsigned r1 = *(const unsigned*)(base + XB_STRIDE);
                unsigned r2 = *(const unsigned*)(base + 2 * XB_STRIDE);
                unsigned r3 = *(const unsigned*)(base + 3 * XB_STRIDE);
                uint2 lo, hi;
                lo.x = (r0 & 0xffffu) | (r1 << 16);        // keys 4g,4g+1 @ d0
                lo.y = (r2 & 0xffffu) | (r3 << 16);        // keys 4g+2,4g+3 @ d0
                hi.x = (r0 >> 16) | (r1 & 0xffff0000u);    // @ d0+1
                hi.y = (r2 >> 16) | (r3 & 0xffff0000u);
                *(uint2*)(lds + XBT_OFF + d0 * XBT_STRIDE + g * 8) = lo;
                *(uint2*)(lds + XBT_OFF + (d0 + 1) * XBT_STRIDE + g * 8) = hi;
            }
        }
        __syncthreads();

        // ---- phase 1: S = Q K^T (wave: 16 rows x 128 keys) ----
        f32x4 sacc[8];
        #pragma unroll
        for (int kf = 0; kf < 8; ++kf) {
            sacc[kf] = (f32x4){0.f, 0.f, 0.f, 0.f};
            const char* rowp = lds + XB_OFF + (kf * 16 + l16) * XB_STRIDE + h * 16;
            #pragma unroll
            for (int ds = 0; ds < 4; ++ds) {
                bf16x8 kfrag = *(const bf16x8*)(rowp + ds * 64);
                sacc[kf] = __builtin_amdgcn_mfma_f32_16x16x32_bf16(
                    qfrag[ds], kfrag, sacc[kf], 0, 0, 0);
            }
        }

        // ---- phase 2: mask + exp + row-sum + P -> LDS (wave-private) ----
        char* prow = lds + P_OFF + w * P_WAVE;
        #pragma unroll
        for (int kf = 0; kf < 8; ++kf) {
            #pragma unroll
            for (int r = 0; r < 4; ++r) {
                float s = sacc[kf][r] * 0.08838834764831845f;  // 1/sqrt(128)
                float p = (av[kf][r] > 0) ? __expf(s) : 0.0f;
                psum[r] += p;
                *(unsigned short*)(prow + (h * 4 + r) * P_STRIDE +
                                   (kf * 16 + l16) * 2) = (unsigned short)f2bf(p);
            }
        }
        __syncthreads();  // also drains lgkm so P writes are readable

        // ---- phase 3: O += P @ V ----
        bf16x8 pfrag[4];
        #pragma unroll
        for (int ks = 0; ks < 4; ++ks)
            pfrag[ks] = *(const bf16x8*)(prow + l16 * P_STRIDE + ks * 64 + h * 16);
        #pragma unroll
        for (int cf = 0; cf < 8; ++cf) {
            const char* vrow = lds + XBT_OFF + (cf * 16 + l16) * XBT_STRIDE;
            #pragma unroll
            for (int ks = 0; ks < 4; ++ks) {
                union { bf16x8 v; uint2 u[2]; } vb;
                vb.u[0] = *(const uint2*)(vrow + ks * 64 + h * 16);
                vb.u[1] = *(const uint2*)(vrow + ks * 64 + h * 16 + 8);
                oacc[cf] = __builtin_amdgcn_mfma_f32_16x16x32_bf16(
                    pfrag[ks], vb.v, oacc[cf], 0, 0, 0);
            }
        }
    }

    // ---- epilogue: row-sum reduce (16-lane butterfly) + normalize + store ----
    float inv[4];
    #pragma unroll
    for (int r = 0; r < 4; ++r) {
        float s = psum[r];
        s += __shfl_xor(s, 1, 16);
        s += __shfl_xor(s, 2, 16);
        s += __shfl_xor(s, 4, 16);
        s += __shfl_xor(s, 8, 16);
        inv[r] = 1.0f / s;
    }
    #pragma unroll
    for (int cf = 0; cf < 8; ++cf)
        #pragma unroll
        for (int r = 0; r < 4; ++r)
            Og[(size_t)(qbase + h * 4 + r) * DD + cf * 16 + l16] =
                oacc[cf][r] * inv[r];
}

extern "C" void kernel_launch(void* const* d_in, const int* in_sizes, int n_in,
                              void* d_out, int out_size, void* d_ws, size_t ws_size,
                              hipStream_t stream) {
    const float* X   = (const float*)d_in[0];
    const int*   adj = (const int*)d_in[1];
    float*       out = (float*)d_out;

    // >64KB LDS needs opt-in; host-side attr set is graph-capture-safe.
    hipFuncSetAttribute((const void*)gat_fused,
                        hipFuncAttributeMaxDynamicSharedMemorySize, LDS_BYTES);
    gat_fused<<<dim3(256), dim3(256), LDS_BYTES, stream>>>(X, adj, out);
}

// Round 2
// 428.569 us; speedup vs baseline: 1.2544x; 1.2544x over previous
//
#include <hip/hip_runtime.h>
#include <hip/hip_bf16.h>

// GAT fused masked attention, B=4 N=4096 D=128 fp32.
// Round 2: occupancy 4x (1024 thr, 16 waves: 4 row-waves x 4 key-quarters),
// bf16 X / X^T precomputed in d_ws by a prepass, main loop stages via
// global_load_lds(16B) with source-side XOR swizzle (LDS linear), swapped
// QK^T (S^T = K*Q^T) so P packs as b64 writes; epilogue combines quarters.
// Needs ws_size >= 8 MB.

#define NN 4096
#define DD 128
#define BK 128

#define XB_OFF   0                      // [128 key][256B] source-swizzled
#define XBT_OFF  32768                  // [128 d][256B]  source-swizzled
#define P_OFF    65536                  // 16 waves x [16 q][80B]
#define P_WSTRIDE 1280
#define LDS_BYTES (P_OFF + 16 * P_WSTRIDE)   // 86016

typedef __attribute__((ext_vector_type(8))) short bf16x8;
typedef __attribute__((ext_vector_type(4))) float f32x4;

static __device__ __forceinline__ unsigned f2bf(float f) {
    union { float f; unsigned u; } v; v.f = f;
    return (v.u + 0x7fffu + ((v.u >> 16) & 1u)) >> 16;  // RNE
}

static __device__ __forceinline__ void gl_lds16(const void* g, void* l) {
    __builtin_amdgcn_global_load_lds(
        (const __attribute__((address_space(1))) unsigned*)g,
        (__attribute__((address_space(3))) unsigned*)l, 16, 0, 0);
}

// ---------------- prepass: X fp32 -> xb (bf16 [b][n][d]) + xbt (bf16 [b][d][n])
__global__ __launch_bounds__(256)
void gat_prep(const float* __restrict__ X, unsigned short* __restrict__ xb,
              unsigned short* __restrict__ xbt) {
    __shared__ unsigned short tile[64][132];   // +4 pad: transposed-read spread
    const int t = threadIdx.x;
    const int b  = blockIdx.x >> 6;
    const int kc = blockIdx.x & 63;            // 64-key chunk
    const float* src = X + ((size_t)b * NN + kc * 64) * DD;
    unsigned short* xbo = xb + ((size_t)b * NN + kc * 64) * DD;

    #pragma unroll
    for (int it = 0; it < 8; ++it) {
        int f = it * 256 + t;                  // float4 index, 2048 total
        int k = f >> 5, d4 = (f & 31) * 4;
        float4 v = *(const float4*)(src + (size_t)f * 4);
        uint2 pk;
        pk.x = f2bf(v.x) | (f2bf(v.y) << 16);
        pk.y = f2bf(v.z) | (f2bf(v.w) << 16);
        *(uint2*)(xbo + (size_t)f * 4) = pk;
        *(uint2*)(&tile[k][d4]) = pk;
    }
    __syncthreads();
    const int d = t >> 1, kb0 = (t & 1) * 32;
    unsigned short* dst = xbt + (size_t)b * DD * NN + (size_t)d * NN + kc * 64 + kb0;
    #pragma unroll
    for (int c = 0; c < 4; ++c) {
        union { uint4 o; unsigned short e[8]; } u;
        #pragma unroll
        for (int j = 0; j < 8; ++j) u.e[j] = tile[kb0 + c * 8 + j][d];
        *(uint4*)(dst + c * 8) = u.o;
    }
}

// ---------------- main fused kernel
__global__ __launch_bounds__(1024, 4)
void gat_fused(const unsigned short* __restrict__ xb,
               const unsigned short* __restrict__ xbt,
               const int* __restrict__ adj,
               float* __restrict__ out) {
    extern __shared__ char lds[];
    const int t = threadIdx.x;
    const int w = t >> 6, l = t & 63;
    const int h = l >> 4, l16 = l & 15;
    const int rw = w & 3;          // row-wave: 16 q rows
    const int kh = w >> 2;         // key quarter: 32 keys/tile

    const int bid  = blockIdx.x;
    const int b    = bid >> 6;
    const int row0 = (bid & 63) * 64;
    const int qbase = row0 + rw * 16;

    const char* xb_b  = (const char*)(xb  + (size_t)b * NN * DD);
    const char* xbt_b = (const char*)(xbt + (size_t)b * DD * NN);
    const int*  Ag    = adj + (size_t)b * NN * NN;
    float*      Og    = out + (size_t)b * NN * DD;

    // Q^T B-frags straight from xb (prepass ordered before us on the stream)
    bf16x8 qfrag[4];
    {
        const char* qp = xb_b + (size_t)(qbase + l16) * DD * 2;
        #pragma unroll
        for (int ds = 0; ds < 4; ++ds)
            qfrag[ds] = *(const bf16x8*)(qp + ds * 64 + h * 16);
    }

    // staging offsets (source-side swizzle: LDS[row][c] = G[row][c ^ (row&7)])
    const int c = l16;
    int off_xb[2], off_xbt[2];
    #pragma unroll
    for (int j = 0; j < 2; ++j) {
        int r0 = w * 8 + 4 * j + h;            // staged row 0..127
        off_xb[j]  = r0 * 256        + ((c ^ (r0 & 7)) * 16);
        off_xbt[j] = r0 * (NN * 2)   + ((c ^ (r0 & 7)) * 16);
    }
    char* ldsXb  = lds + XB_OFF  + w * 2048;
    char* ldsXbt = lds + XBT_OFF + w * 2048;
    char* pw     = lds + P_OFF   + w * P_WSTRIDE;
    const int kbase = kh * 32;

    f32x4 oacc[8];
    #pragma unroll
    for (int cf = 0; cf < 8; ++cf) oacc[cf] = (f32x4){0.f, 0.f, 0.f, 0.f};
    float psum = 0.f;

    for (int kt = 0; kt < NN / BK; ++kt) {
        const int key0 = kt * BK;

        // adj prefetch (int4: q = l16 row, 4 consecutive keys x2 frag-groups)
        int4 av[2];
        #pragma unroll
        for (int f = 0; f < 2; ++f)
            av[f] = *(const int4*)(Ag + (size_t)(qbase + l16) * NN
                                      + key0 + kbase + f * 16 + 4 * h);

        __syncthreads();                       // prev tile fully consumed

        #pragma unroll
        for (int j = 0; j < 2; ++j) {          // 4 x 1KB direct-to-LDS per wave
            gl_lds16(xb_b  + key0 * 256 + off_xb[j],  ldsXb  + j * 1024);
            gl_lds16(xbt_b + key0 * 2   + off_xbt[j], ldsXbt + j * 1024);
        }
        __syncthreads();                       // stage visible (vmcnt drained)

        // QK^T swapped: S^T = K * Q^T  (lane holds q=l16, keys 4h+r+16f)
        f32x4 sacc[2];
        #pragma unroll
        for (int f = 0; f < 2; ++f) {
            sacc[f] = (f32x4){0.f, 0.f, 0.f, 0.f};
            const int krow = kbase + f * 16 + l16;
            const char* rp = lds + XB_OFF + krow * 256;
            const int sw = krow & 7;
            #pragma unroll
            for (int ds = 0; ds < 4; ++ds) {
                bf16x8 kf_ = *(const bf16x8*)(rp + ((h + 4 * ds) ^ sw) * 16);
                sacc[f] = __builtin_amdgcn_mfma_f32_16x16x32_bf16(
                    kf_, qfrag[ds], sacc[f], 0, 0, 0);
            }
        }

        // mask + exp + packed P write (b64, conflict-free 80B stride)
        #pragma unroll
        for (int f = 0; f < 2; ++f) {
            const float SC = 0.08838834764831845f;  // 1/sqrt(128)
            float p0 = (av[f].x > 0) ? __expf(sacc[f][0] * SC) : 0.f;
            float p1 = (av[f].y > 0) ? __expf(sacc[f][1] * SC) : 0.f;
            float p2 = (av[f].z > 0) ? __expf(sacc[f][2] * SC) : 0.f;
            float p3 = (av[f].w > 0) ? __expf(sacc[f][3] * SC) : 0.f;
            psum += p0 + p1 + p2 + p3;
            uint2 pk;
            pk.x = f2bf(p0) | (f2bf(p1) << 16);
            pk.y = f2bf(p2) | (f2bf(p3) << 16);
            *(uint2*)(pw + l16 * 80 + f * 32 + h * 8) = pk;
        }

        // PV: O += P * V  (P wave-private; in-order DS pipe, no barrier needed)
        bf16x8 pfrag = *(const bf16x8*)(pw + l16 * 80 + h * 16);
        #pragma unroll
        for (int cf = 0; cf < 8; ++cf) {
            const int vrow = l16 + 16 * cf;
            bf16x8 vfrag = *(const bf16x8*)(lds + XBT_OFF + vrow * 256
                                + (((4 * kh + h) ^ (vrow & 7)) * 16));
            oacc[cf] = __builtin_amdgcn_mfma_f32_16x16x32_bf16(
                pfrag, vfrag, oacc[cf], 0, 0, 0);
        }
    }

    // ---------------- epilogue: combine 4 key-quarters, normalize, store
    psum += __shfl_xor(psum, 16, 64);
    psum += __shfl_xor(psum, 32, 64);

    __syncthreads();
    float* psarea = (float*)(lds + P_OFF);     // [kh*4+rw][16]
    if (l < 16) psarea[(kh * 4 + rw) * 16 + l] = psum;
    float* oa = (float*)lds;                   // 2 slots x [4 rw][16][128] f32
    if (kh >= 2) {
        float* dst = oa + ((kh - 2) * 4 + rw) * 2048;
        #pragma unroll
        for (int cf = 0; cf < 8; ++cf)
            #pragma unroll
            for (int r = 0; r < 4; ++r)
                dst[(4 * h + r) * 128 + l16 + 16 * cf] = oacc[cf][r];
    }
    __syncthreads();
    if (kh < 2) {
        const float* sp = oa + (kh * 4 + rw) * 2048;
        #pragma unroll
        for (int cf = 0; cf < 8; ++cf)
            #pragma unroll
            for (int r = 0; r < 4; ++r)
                oacc[cf][r] += sp[(4 * h + r) * 128 + l16 + 16 * cf];
    }
    __syncthreads();
    if (kh == 1) {
        float* dst = oa + rw * 2048;
        #pragma unroll
        for (int cf = 0; cf < 8; ++cf)
            #pragma unroll
            for (int r = 0; r < 4; ++r)
                dst[(4 * h + r) * 128 + l16 + 16 * cf] = oacc[cf][r];
    }
    __syncthreads();
    if (kh == 0) {
        const float* sp = oa + rw * 2048;
        float inv[4];
        #pragma unroll
        for (int r = 0; r < 4; ++r) {
            int q = 4 * h + r;
            float tot = psarea[rw * 16 + q]        + psarea[(4 + rw) * 16 + q]
                      + psarea[(8 + rw) * 16 + q]  + psarea[(12 + rw) * 16 + q];
            inv[r] = 1.0f / tot;
        }
        float* dst = oa + rw * 2048;               // write back final rows
        #pragma unroll
        for (int cf = 0; cf < 8; ++cf)
            #pragma unroll
            for (int r = 0; r < 4; ++r)
                dst[(4 * h + r) * 128 + l16 + 16 * cf] =
                    (oacc[cf][r] + sp[(4 * h + r) * 128 + l16 + 16 * cf]) * inv[r];
    }
    __syncthreads();
    // coalesced store of the whole 64x128 block
    const float4* oaf4 = (const float4*)oa;
    float4* dstf4 = (float4*)(Og + (size_t)row0 * DD);
    dstf4[t]        = oaf4[t];
    dstf4[t + 1024] = oaf4[t + 1024];
}

extern "C" void kernel_launch(void* const* d_in, const int* in_sizes, int n_in,
                              void* d_out, int out_size, void* d_ws, size_t ws_size,
                              hipStream_t stream) {
    const float* X   = (const float*)d_in[0];
    const int*   adj = (const int*)d_in[1];
    float*       out = (float*)d_out;
    unsigned short* xb  = (unsigned short*)d_ws;              // 4 MB
    unsigned short* xbt = xb + (size_t)4 * NN * DD * 2;       // wait: elements
    // xb holds 4*4096*128 = 2,097,152 bf16 elements; xbt follows.
    xbt = xb + (size_t)4 * NN * DD;

    hipFuncSetAttribute((const void*)gat_fused,
                        hipFuncAttributeMaxDynamicSharedMemorySize, LDS_BYTES);
    gat_prep<<<dim3(256), dim3(256), 0, stream>>>(X, xb, xbt);
    gat_fused<<<dim3(256), dim3(1024), LDS_BYTES, stream>>>(xb, xbt, adj, out);
}

// Round 4
// 399.907 us; speedup vs baseline: 1.3443x; 1.0717x over previous
//
#include <hip/hip_runtime.h>
#include <hip/hip_bf16.h>

// GAT fused masked attention, B=4 N=4096 D=128 fp32.
// Round 3 (resubmit; prior round hit broker timeout, never ran):
// software-pipelined main loop (raw s_barrier + counted vmcnt(2),
// double-buffered LDS tiles, adj prefetched 1 tile ahead into regs) so the
// per-tile HBM adj read + L2 tile stage hide under compute. One barrier/tile.
// Needs ws_size >= 8 MB.

#define NN 4096
#define DD 128
#define BK 128
#define NT (NN / BK)

#define XBT_REL 32768                    // XBT offset within a buffer
#define BUF1_OFF 65536
#define P_OFF 131072                     // 16 waves x [16 q][80B]
#define P_WSTRIDE 1280
#define LDS_BYTES (P_OFF + 16 * P_WSTRIDE)   // 151552

typedef __attribute__((ext_vector_type(8))) short bf16x8;
typedef __attribute__((ext_vector_type(4))) float f32x4;

static __device__ __forceinline__ unsigned f2bf(float f) {
    union { float f; unsigned u; } v; v.f = f;
    return (v.u + 0x7fffu + ((v.u >> 16) & 1u)) >> 16;  // RNE
}

static __device__ __forceinline__ void gl_lds16(const void* g, void* l) {
    __builtin_amdgcn_global_load_lds(
        (const __attribute__((address_space(1))) unsigned*)g,
        (__attribute__((address_space(3))) unsigned*)l, 16, 0, 0);
}

// ---------------- prepass: X fp32 -> xb (bf16 [b][n][d]) + xbt (bf16 [b][d][n])
__global__ __launch_bounds__(256)
void gat_prep(const float* __restrict__ X, unsigned short* __restrict__ xb,
              unsigned short* __restrict__ xbt) {
    __shared__ unsigned short tile[64][132];
    const int t = threadIdx.x;
    const int b  = blockIdx.x >> 6;
    const int kc = blockIdx.x & 63;
    const float* src = X + ((size_t)b * NN + kc * 64) * DD;
    unsigned short* xbo = xb + ((size_t)b * NN + kc * 64) * DD;

    #pragma unroll
    for (int it = 0; it < 8; ++it) {
        int f = it * 256 + t;
        int k = f >> 5, d4 = (f & 31) * 4;
        float4 v = *(const float4*)(src + (size_t)f * 4);
        uint2 pk;
        pk.x = f2bf(v.x) | (f2bf(v.y) << 16);
        pk.y = f2bf(v.z) | (f2bf(v.w) << 16);
        *(uint2*)(xbo + (size_t)f * 4) = pk;
        *(uint2*)(&tile[k][d4]) = pk;
    }
    __syncthreads();
    const int d = t >> 1, kb0 = (t & 1) * 32;
    unsigned short* dst = xbt + (size_t)b * DD * NN + (size_t)d * NN + kc * 64 + kb0;
    #pragma unroll
    for (int c = 0; c < 4; ++c) {
        union { uint4 o; unsigned short e[8]; } u;
        #pragma unroll
        for (int j = 0; j < 8; ++j) u.e[j] = tile[kb0 + c * 8 + j][d];
        *(uint4*)(dst + c * 8) = u.o;
    }
}

// ---------------- main fused kernel
__global__ __launch_bounds__(1024, 4)
void gat_fused(const unsigned short* __restrict__ xb,
               const unsigned short* __restrict__ xbt,
               const int* __restrict__ adj,
               float* __restrict__ out) {
    extern __shared__ char lds[];
    const int t = threadIdx.x;
    const int w = t >> 6, l = t & 63;
    const int h = l >> 4, l16 = l & 15;
    const int rw = w & 3;          // row-wave: 16 q rows
    const int kh = w >> 2;         // key quarter: 32 keys/tile

    const int bid  = blockIdx.x;
    const int b    = bid >> 6;
    const int row0 = (bid & 63) * 64;
    const int qbase = row0 + rw * 16;
    const int kbase = kh * 32;

    const char* xb_b  = (const char*)(xb  + (size_t)b * NN * DD);
    const char* xbt_b = (const char*)(xbt + (size_t)b * DD * NN);
    const int*  Ag    = adj + (size_t)b * NN * NN;
    float*      Og    = out + (size_t)b * NN * DD;

    // Q^T B-frags from xb (global, once)
    bf16x8 qfrag[4];
    {
        const char* qp = xb_b + (size_t)(qbase + l16) * DD * 2;
        #pragma unroll
        for (int ds = 0; ds < 4; ++ds)
            qfrag[ds] = *(const bf16x8*)(qp + ds * 64 + h * 16);
    }

    // source-side swizzle offsets: LDS[r0][c] = G[r0][c ^ (r0&7)]
    int off_xb[2], off_xbt[2];
    #pragma unroll
    for (int j = 0; j < 2; ++j) {
        int r0 = w * 8 + 4 * j + h;
        off_xb[j]  = r0 * 256      + ((l16 ^ (r0 & 7)) * 16);
        off_xbt[j] = r0 * (NN * 2) + ((l16 ^ (r0 & 7)) * 16);
    }
    char* bufA = lds;                 // current tile
    char* bufB = lds + BUF1_OFF;      // next tile
    char* pw   = lds + P_OFF + w * P_WSTRIDE;

    const int* arow = Ag + (size_t)(qbase + l16) * NN + kbase + 4 * h;

    // ---- prologue: stage tile 0 + adj tile 0 ----
    #pragma unroll
    for (int j = 0; j < 2; ++j) {
        gl_lds16(xb_b  + off_xb[j],  bufA + w * 2048 + j * 1024);
        gl_lds16(xbt_b + off_xbt[j], bufA + XBT_REL + w * 2048 + j * 1024);
    }
    int4 avA0 = *(const int4*)(arow);
    int4 avA1 = *(const int4*)(arow + 16);

    f32x4 oacc[8];
    #pragma unroll
    for (int cf = 0; cf < 8; ++cf) oacc[cf] = (f32x4){0.f, 0.f, 0.f, 0.f};
    float psum = 0.f;

#define COMPUTE(BUF, AV0, AV1) do {                                            \
    f32x4 sacc0 = (f32x4){0.f,0.f,0.f,0.f}, sacc1 = (f32x4){0.f,0.f,0.f,0.f};  \
    {                                                                          \
        const int krow0 = kbase + l16;                                         \
        const int krow1 = kbase + 16 + l16;                                    \
        const char* rp0 = (BUF) + krow0 * 256;                                 \
        const char* rp1 = (BUF) + krow1 * 256;                                 \
        const int sw = l16 & 7;                                                \
        _Pragma("unroll")                                                      \
        for (int ds = 0; ds < 4; ++ds) {                                       \
            bf16x8 kf0 = *(const bf16x8*)(rp0 + (((h + 4*ds) ^ sw) * 16));     \
            sacc0 = __builtin_amdgcn_mfma_f32_16x16x32_bf16(                   \
                kf0, qfrag[ds], sacc0, 0, 0, 0);                               \
            bf16x8 kf1 = *(const bf16x8*)(rp1 + (((h + 4*ds) ^ sw) * 16));     \
            sacc1 = __builtin_amdgcn_mfma_f32_16x16x32_bf16(                   \
                kf1, qfrag[ds], sacc1, 0, 0, 0);                               \
        }                                                                      \
    }                                                                          \
    {                                                                          \
        const float SC = 0.08838834764831845f;                                 \
        float p0 = ((AV0).x > 0) ? __expf(sacc0[0] * SC) : 0.f;                \
        float p1 = ((AV0).y > 0) ? __expf(sacc0[1] * SC) : 0.f;                \
        float p2 = ((AV0).z > 0) ? __expf(sacc0[2] * SC) : 0.f;                \
        float p3 = ((AV0).w > 0) ? __expf(sacc0[3] * SC) : 0.f;                \
        psum += p0 + p1 + p2 + p3;                                             \
        uint2 pk0; pk0.x = f2bf(p0) | (f2bf(p1) << 16);                        \
        pk0.y = f2bf(p2) | (f2bf(p3) << 16);                                   \
        *(uint2*)(pw + l16 * 80 + h * 8) = pk0;                                \
        float q0 = ((AV1).x > 0) ? __expf(sacc1[0] * SC) : 0.f;                \
        float q1 = ((AV1).y > 0) ? __expf(sacc1[1] * SC) : 0.f;                \
        float q2 = ((AV1).z > 0) ? __expf(sacc1[2] * SC) : 0.f;                \
        float q3 = ((AV1).w > 0) ? __expf(sacc1[3] * SC) : 0.f;                \
        psum += q0 + q1 + q2 + q3;                                             \
        uint2 pk1; pk1.x = f2bf(q0) | (f2bf(q1) << 16);                        \
        pk1.y = f2bf(q2) | (f2bf(q3) << 16);                                   \
        *(uint2*)(pw + l16 * 80 + 32 + h * 8) = pk1;                           \
    }                                                                          \
    {                                                                          \
        bf16x8 pfrag = *(const bf16x8*)(pw + l16 * 80 + h * 16);               \
        _Pragma("unroll")                                                      \
        for (int cf = 0; cf < 8; ++cf) {                                       \
            const int vrow = l16 + 16 * cf;                                    \
            bf16x8 vfrag = *(const bf16x8*)((BUF) + XBT_REL + vrow * 256       \
                              + (((4*kh + h) ^ (vrow & 7)) * 16));             \
            oacc[cf] = __builtin_amdgcn_mfma_f32_16x16x32_bf16(                \
                pfrag, vfrag, oacc[cf], 0, 0, 0);                              \
        }                                                                      \
    }                                                                          \
} while (0)

    // ---- pipelined main loop: one barrier per tile, counted vmcnt ----
    for (int kt = 0; kt < NT - 1; ++kt) {
        // adj prefetch for tile kt+1 (regs; consumed next iter)
        int4 avB0 = *(const int4*)(arow + (kt + 1) * BK);
        int4 avB1 = *(const int4*)(arow + (kt + 1) * BK + 16);
        // own stage(kt) complete (only the 2 adj loads above may remain)
        asm volatile("s_waitcnt vmcnt(2)" ::: "memory");
        // all waves: stage(kt) done + reads of bufB (tile kt-1) retired
        __builtin_amdgcn_s_barrier();
        // stage tile kt+1 into bufB — flies under COMPUTE
        #pragma unroll
        for (int j = 0; j < 2; ++j) {
            gl_lds16(xb_b  + (size_t)(kt + 1) * BK * 256 + off_xb[j],
                     bufB + w * 2048 + j * 1024);
            gl_lds16(xbt_b + (size_t)(kt + 1) * BK * 2 + off_xbt[j],
                     bufB + XBT_REL + w * 2048 + j * 1024);
        }
        COMPUTE(bufA, avA0, avA1);
        char* tmp = bufA; bufA = bufB; bufB = tmp;
        avA0 = avB0; avA1 = avB1;
    }
    // tail tile
    asm volatile("s_waitcnt vmcnt(0)" ::: "memory");
    __builtin_amdgcn_s_barrier();
    COMPUTE(bufA, avA0, avA1);

    // ---------------- epilogue: combine 4 key-quarters, normalize, store
    psum += __shfl_xor(psum, 16, 64);
    psum += __shfl_xor(psum, 32, 64);

    __syncthreads();
    float* psarea = (float*)(lds + P_OFF);     // [w][16]
    if (l < 16) psarea[w * 16 + l] = psum;
    float* oa = (float*)lds;                   // 2 slots x [4 rw][16][128] f32
    if (kh >= 2) {
        float* dst = oa + ((kh - 2) * 4 + rw) * 2048;
        #pragma unroll
        for (int cf = 0; cf < 8; ++cf)
            #pragma unroll
            for (int r = 0; r < 4; ++r)
                dst[(4 * h + r) * 128 + l16 + 16 * cf] = oacc[cf][r];
    }
    __syncthreads();
    if (kh < 2) {
        const float* sp = oa + (kh * 4 + rw) * 2048;
        #pragma unroll
        for (int cf = 0; cf < 8; ++cf)
            #pragma unroll
            for (int r = 0; r < 4; ++r)
                oacc[cf][r] += sp[(4 * h + r) * 128 + l16 + 16 * cf];
    }
    __syncthreads();
    if (kh == 1) {
        float* dst = oa + rw * 2048;
        #pragma unroll
        for (int cf = 0; cf < 8; ++cf)
            #pragma unroll
            for (int r = 0; r < 4; ++r)
                dst[(4 * h + r) * 128 + l16 + 16 * cf] = oacc[cf][r];
    }
    __syncthreads();
    if (kh == 0) {
        const float* sp = oa + rw * 2048;
        float inv[4];
        #pragma unroll
        for (int r = 0; r < 4; ++r) {
            int q = 4 * h + r;
            float tot = psarea[rw * 16 + q]       + psarea[(4 + rw) * 16 + q]
                      + psarea[(8 + rw) * 16 + q] + psarea[(12 + rw) * 16 + q];
            inv[r] = 1.0f / tot;
        }
        float* dst = oa + rw * 2048;
        #pragma unroll
        for (int cf = 0; cf < 8; ++cf)
            #pragma unroll
            for (int r = 0; r < 4; ++r)
                dst[(4 * h + r) * 128 + l16 + 16 * cf] =
                    (oacc[cf][r] + sp[(4 * h + r) * 128 + l16 + 16 * cf]) * inv[r];
    }
    __syncthreads();
    const float4* oaf4 = (const float4*)oa;
    float4* dstf4 = (float4*)(Og + (size_t)row0 * DD);
    dstf4[t]        = oaf4[t];
    dstf4[t + 1024] = oaf4[t + 1024];
#undef COMPUTE
}

extern "C" void kernel_launch(void* const* d_in, const int* in_sizes, int n_in,
                              void* d_out, int out_size, void* d_ws, size_t ws_size,
                              hipStream_t stream) {
    const float* X   = (const float*)d_in[0];
    const int*   adj = (const int*)d_in[1];
    float*       out = (float*)d_out;
    unsigned short* xb  = (unsigned short*)d_ws;              // 4 MB bf16 X
    unsigned short* xbt = xb + (size_t)4 * NN * DD;           // 4 MB bf16 X^T

    hipFuncSetAttribute((const void*)gat_fused,
                        hipFuncAttributeMaxDynamicSharedMemorySize, LDS_BYTES);
    gat_prep<<<dim3(256), dim3(256), 0, stream>>>(X, xb, xbt);
    gat_fused<<<dim3(256), dim3(1024), LDS_BYTES, stream>>>(xb, xbt, adj, out);
}